// Round 4
// baseline (61.422 us; speedup 1.0000x reference)
//
#include <hip/hip_runtime.h>
#include <stdint.h>

// CachedCompressedLinear: out[b][o] = sum_k x[b][k] * ((wq[o][k]-128)*scale) + bias[o]
// x: [16][4096] f32, wq: [11008][4096] int32 codes, scale f32, bias[11008] f32.
//
// R3 (LDS-staged, __syncthreads) = 55us: compiler drains vmcnt(0) at every
// barrier -> stop-and-go. R4: T3/T4 counted-vmcnt pipeline (m218 pattern):
// raw s_barrier + asm vmcnt(N), 16KB chunks, 3 LDS buffers, depth-2 prefetch.
// Loads stay in flight ACROSS barriers; never vmcnt(0) in steady state.

constexpr int IN_F  = 4096;
constexpr int OUT_F = 11008;
constexpr int NWAVES = 8;
constexpr int BK     = 256;                 // ints per chunk per row
constexpr int NCHUNK = IN_F / BK;           // 16
constexpr int ROW_B  = BK * 4;              // 1024 B per row per chunk
constexpr int CH_B   = 16 * ROW_B;          // 16 KB per chunk
constexpr int NBUF   = 3;                   // 48 KB + 8 KB reduce = 56 KB LDS

typedef _Float16 f16x8 __attribute__((ext_vector_type(8)));
typedef float    f32x4 __attribute__((ext_vector_type(4)));

__device__ inline f16x8 cvt_codes(int4 a, int4 b) {
    f16x8 r;   // codes in [0,255]; (c-128) exact in f16
    r[0] = (_Float16)(a.x - 128); r[1] = (_Float16)(a.y - 128);
    r[2] = (_Float16)(a.z - 128); r[3] = (_Float16)(a.w - 128);
    r[4] = (_Float16)(b.x - 128); r[5] = (_Float16)(b.y - 128);
    r[6] = (_Float16)(b.z - 128); r[7] = (_Float16)(b.w - 128);
    return r;
}

__global__ __launch_bounds__(NWAVES * 64)
void qlinear_mfma(const float* __restrict__ x,
                  const int*   __restrict__ wq,
                  const float* __restrict__ scale,
                  const float* __restrict__ bias,
                  float*       __restrict__ out)
{
    __shared__ __align__(16) char smem[NBUF * CH_B];   // 48 KB w buffers
    __shared__ f32x4 red[NWAVES][64];                  // 8 KB reduce

    const int tid  = threadIdx.x;
    const int lane = tid & 63;
    const int wave = tid >> 6;
    const int obase = blockIdx.x * 16;

    const int ncol = lane & 15;   // B col (o_local) == A row (batch)
    const int kgrp = lane >> 4;   // 0..3

    // ---- hoist x A-fragments: a[c] covers k = c*256 + wave*32 + kgrp*8 + [0,8) ----
    f16x8 a[NCHUNK];
    {
        const float* xp = x + (size_t)ncol * IN_F + wave * 32 + kgrp * 8;
        #pragma unroll
        for (int c = 0; c < NCHUNK; ++c) {
            const float4 xa = *reinterpret_cast<const float4*>(xp + c * BK);
            const float4 xb = *reinterpret_cast<const float4*>(xp + c * BK + 4);
            f16x8 t;
            t[0] = (_Float16)xa.x; t[1] = (_Float16)xa.y;
            t[2] = (_Float16)xa.z; t[3] = (_Float16)xa.w;
            t[4] = (_Float16)xb.x; t[5] = (_Float16)xb.y;
            t[6] = (_Float16)xb.z; t[7] = (_Float16)xb.w;
            a[c] = t;
        }
    }

    // ---- staging: wave-contiguous 1KB reads; linear LDS dest; source
    //      pre-swizzled with the same involution the reader applies (rule #21) ----
    const char* wq_bytes = reinterpret_cast<const char*>(wq);
    auto stage = [&](int c, int buf) {
        #pragma unroll
        for (int p = 0; p < 2; ++p) {
            const int row = wave * 2 + p;                       // 0..15
            const int within = (lane * 16) ^ ((row & 7) << 4);  // wave-uniform XOR
            const char* src = wq_bytes + (size_t)(obase + row) * (IN_F * 4)
                                       + (size_t)c * ROW_B + within;
            char* dst = smem + buf * CH_B + row * ROW_B + lane * 16;
            __builtin_amdgcn_global_load_lds(
                (const __attribute__((address_space(1))) void*)src,
                (__attribute__((address_space(3))) void*)dst, 16, 0, 0);
        }
    };

    // drain x loads so the vmcnt ledger below counts ONLY stage loads
    asm volatile("s_waitcnt vmcnt(0)" ::: "memory");
    __builtin_amdgcn_sched_barrier(0);

    stage(0, 0);
    stage(1, 1);          // outstanding: 4 loads/wave (chunks 0,1)

    f32x4 acc = {0.f, 0.f, 0.f, 0.f};
    const int swz = (ncol & 7) << 4;
    const int lo  = wave * 128 + kgrp * 32;   // logical byte offset in row

    #pragma unroll
    for (int c = 0; c < NCHUNK; ++c) {
        // retire chunk c's 2 loads; keep chunk c+1's flying (never drain to 0
        // in steady state)
        if (c < NCHUNK - 1) asm volatile("s_waitcnt vmcnt(2)" ::: "memory");
        else                asm volatile("s_waitcnt vmcnt(0)" ::: "memory");
        __builtin_amdgcn_s_barrier();
        __builtin_amdgcn_sched_barrier(0);

        if (c + 2 < NCHUNK) stage(c + 2, (c + 2) % NBUF);  // prefetch (outstanding->4)

        const char* rowbase = smem + (c % NBUF) * CH_B + ncol * ROW_B;
        const int4 w0 = *reinterpret_cast<const int4*>(rowbase + ((lo)      ^ swz));
        const int4 w1 = *reinterpret_cast<const int4*>(rowbase + ((lo + 16) ^ swz));
        acc = __builtin_amdgcn_mfma_f32_16x16x32_f16(a[c], cvt_codes(w0, w1), acc, 0, 0, 0);
        __builtin_amdgcn_sched_barrier(0);
    }

    // ---- reduce 8 per-wave partials (disjoint k subsets) ----
    red[wave][lane] = acc;
    __syncthreads();

    if (wave == 0) {
        f32x4 s = red[0][lane];
        #pragma unroll
        for (int w = 1; w < NWAVES; ++w) s += red[w][lane];

        const float sc = scale[0];
        const float bo = bias[obase + ncol];
        const int   brow = kgrp * 4;   // C/D: col=lane&15 -> o, row=(lane>>4)*4+r -> batch
        #pragma unroll
        for (int r = 0; r < 4; ++r)
            out[(size_t)(brow + r) * OUT_F + obase + ncol] = s[r] * sc + bo;
    }
}

extern "C" void kernel_launch(void* const* d_in, const int* in_sizes, int n_in,
                              void* d_out, int out_size, void* d_ws, size_t ws_size,
                              hipStream_t stream) {
    const float* x     = (const float*)d_in[0];
    const int*   wq    = (const int*)d_in[1];
    const float* scale = (const float*)d_in[2];
    const float* bias  = (const float*)d_in[3];
    float*       out   = (float*)d_out;

    dim3 grid(OUT_F / 16);        // 688 o-tiles
    dim3 block(NWAVES * 64);      // 512 threads
    qlinear_mfma<<<grid, block, 0, stream>>>(x, wq, scale, bias, out);
}

// Round 6
// 55.539 us; speedup vs baseline: 1.1059x; 1.1059x over previous
//
#include <hip/hip_runtime.h>
#include <stdint.h>

// CachedCompressedLinear: out[b][o] = sum_k x[b][k] * ((wq[o][k]-128)*scale) + bias[o]
// x: [16][4096] f32, wq: [11008][4096] int32 codes, scale f32, bias[11008] f32.
//
// R1..R4 all pinned at 49-61us (~3.7 TB/s on the mandatory 180MB wq read)
// across four different structures -> limiter is the read path, not the
// kernel schedule. R5/R6 theory: L1 line allocation caps outstanding misses
// (reads ~4 TB/s; writes hit 7.2). Fix: NONTEMPORAL wq loads (no L1 alloc,
// wq has zero reuse) on the simplest low-VGPR loop (max waves/CU), plus
// per-block wave->k-slice rotation to decorrelate DRAM banks across blocks.
// (R5 failed to compile: nontemporal builtin needs ext_vector_type, not
// HIP_vector_type. R6 = same kernel with clang vector types.)

constexpr int IN_F  = 4096;
constexpr int OUT_F = 11008;
constexpr int NWAVES = 8;
constexpr int KPW = IN_F / NWAVES;   // 512 k per wave
constexpr int NKB = KPW / 32;        // 16 k-blocks of 32 per wave

typedef _Float16 f16x8 __attribute__((ext_vector_type(8)));
typedef float    f32x4 __attribute__((ext_vector_type(4)));
typedef int      i32x4 __attribute__((ext_vector_type(4)));

__global__ __launch_bounds__(NWAVES * 64)
void qlinear_mfma(const float* __restrict__ x,
                  const int*   __restrict__ wq,
                  const float* __restrict__ scale,
                  const float* __restrict__ bias,
                  float*       __restrict__ out)
{
    const int tid  = threadIdx.x;
    const int lane = tid & 63;
    const int wave = tid >> 6;
    const int obase = blockIdx.x * 16;

    const int ncol = lane & 15;   // B col (o_local) == A row (batch)
    const int kgrp = lane >> 4;   // 0..3

    const int o = obase + ncol;

    // rotate wave->k-slice assignment per block: co-resident blocks touch
    // different k columns of the 16KB-strided row space at any instant
    const int kslice = (wave + (int)blockIdx.x) & (NWAVES - 1);
    const int k0 = kslice * KPW + kgrp * 8;

    const float* xp = x  + (size_t)ncol * IN_F + k0;
    const int*   wp = wq + (size_t)o    * IN_F + k0;

    f32x4 acc = {0.f, 0.f, 0.f, 0.f};

    #pragma unroll
    for (int kb = 0; kb < NKB; ++kb) {
        const int off = kb * 32;
        const f32x4 xa = *reinterpret_cast<const f32x4*>(xp + off);
        const f32x4 xb = *reinterpret_cast<const f32x4*>(xp + off + 4);
        // nontemporal: wq is a 180MB single-use stream; don't allocate in L1
        const i32x4 wa = __builtin_nontemporal_load(
            reinterpret_cast<const i32x4*>(wp + off));
        const i32x4 wb = __builtin_nontemporal_load(
            reinterpret_cast<const i32x4*>(wp + off + 4));

        f16x8 af, bf;
        af[0] = (_Float16)xa[0]; af[1] = (_Float16)xa[1];
        af[2] = (_Float16)xa[2]; af[3] = (_Float16)xa[3];
        af[4] = (_Float16)xb[0]; af[5] = (_Float16)xb[1];
        af[6] = (_Float16)xb[2]; af[7] = (_Float16)xb[3];

        // codes in [0,255]; (c-128) in [-128,127] is EXACT in f16
        bf[0] = (_Float16)(wa[0] - 128); bf[1] = (_Float16)(wa[1] - 128);
        bf[2] = (_Float16)(wa[2] - 128); bf[3] = (_Float16)(wa[3] - 128);
        bf[4] = (_Float16)(wb[0] - 128); bf[5] = (_Float16)(wb[1] - 128);
        bf[6] = (_Float16)(wb[2] - 128); bf[7] = (_Float16)(wb[3] - 128);

        acc = __builtin_amdgcn_mfma_f32_16x16x32_f16(af, bf, acc, 0, 0, 0);
    }

    // ---- reduce the 8 per-wave partials (disjoint k subsets) ----
    __shared__ f32x4 red[NWAVES][64];
    red[wave][lane] = acc;
    __syncthreads();

    if (wave == 0) {
        f32x4 s = red[0][lane];
        #pragma unroll
        for (int w = 1; w < NWAVES; ++w) s += red[w][lane];

        const float sc = scale[0];
        const float bo = bias[o];
        const int   brow = kgrp * 4;   // C/D: col=lane&15 -> o, row=(lane>>4)*4+r -> batch
        #pragma unroll
        for (int r = 0; r < 4; ++r)
            out[(size_t)(brow + r) * OUT_F + o] = s[r] * sc + bo;
    }
}

extern "C" void kernel_launch(void* const* d_in, const int* in_sizes, int n_in,
                              void* d_out, int out_size, void* d_ws, size_t ws_size,
                              hipStream_t stream) {
    const float* x     = (const float*)d_in[0];
    const int*   wq    = (const int*)d_in[1];
    const float* scale = (const float*)d_in[2];
    const float* bias  = (const float*)d_in[3];
    float*       out   = (float*)d_out;

    dim3 grid(OUT_F / 16);        // 688 o-tiles
    dim3 block(NWAVES * 64);      // 512 threads
    qlinear_mfma<<<grid, block, 0, stream>>>(x, wq, scale, bias, out);
}

// Round 7
// 50.114 us; speedup vs baseline: 1.2256x; 1.1083x over previous
//
#include <hip/hip_runtime.h>
#include <stdint.h>

// CachedCompressedLinear: out[b][o] = sum_k x[b][k] * ((wq[o][k]-128)*scale) + bias[o]
// x: [16][4096] f32, wq: [11008][4096] int32 codes, scale f32, bias[11008] f32.
//
// R7: coalesced global_load_lds streaming with the m201/T3+T4 discipline:
//  - 16 KB chunks, NBUF=4, depth-3 prefetch (96 KB/CU reads in flight)
//  - counted s_waitcnt vmcnt(4) (never 0 in steady state), raw s_barrier
//  - NO sched_barrier(0) (R4's m141-style poison), compiler schedules freely
//  - XOR-swizzled LDS (linear dest + pre-swizzled source + swizzled read),
//    2-way residual conflict per 16-lane quarter = free (m136)
// Indexing identical to R4 (absmax 1.0 verified).

constexpr int IN_F  = 4096;
constexpr int OUT_F = 11008;
constexpr int NWAVES = 8;
constexpr int BK     = 256;                 // ints per chunk per row
constexpr int NCHUNK = IN_F / BK;           // 16
constexpr int ROW_B  = BK * 4;              // 1024 B per row per chunk
constexpr int CH_B   = 16 * ROW_B;          // 16 KB per chunk
constexpr int NBUF   = 4;                   // 64 KB + 8 KB reduce = 72 KB LDS

typedef _Float16 f16x8 __attribute__((ext_vector_type(8)));
typedef float    f32x4 __attribute__((ext_vector_type(4)));

__device__ inline f16x8 cvt_codes(int4 a, int4 b) {
    f16x8 r;   // codes in [0,255]; (c-128) exact in f16
    r[0] = (_Float16)(a.x - 128); r[1] = (_Float16)(a.y - 128);
    r[2] = (_Float16)(a.z - 128); r[3] = (_Float16)(a.w - 128);
    r[4] = (_Float16)(b.x - 128); r[5] = (_Float16)(b.y - 128);
    r[6] = (_Float16)(b.z - 128); r[7] = (_Float16)(b.w - 128);
    return r;
}

__global__ __launch_bounds__(NWAVES * 64, 4)   // 4 waves/SIMD -> 2 blocks/CU
void qlinear_mfma(const float* __restrict__ x,
                  const int*   __restrict__ wq,
                  const float* __restrict__ scale,
                  const float* __restrict__ bias,
                  float*       __restrict__ out)
{
    __shared__ __align__(16) char smem[NBUF * CH_B];   // 64 KB w buffers
    __shared__ f32x4 red[NWAVES][64];                  // 8 KB reduce

    const int tid  = threadIdx.x;
    const int lane = tid & 63;
    const int wave = tid >> 6;
    const int obase = blockIdx.x * 16;

    const int ncol = lane & 15;   // B col (o_local) == A row (batch)
    const int kgrp = lane >> 4;   // 0..3

    // ---- hoist x A-fragments: a[c] covers k = c*256 + wave*32 + kgrp*8 + [0,8) ----
    f16x8 a[NCHUNK];
    {
        const float* xp = x + (size_t)ncol * IN_F + wave * 32 + kgrp * 8;
        #pragma unroll
        for (int c = 0; c < NCHUNK; ++c) {
            const float4 xa = *reinterpret_cast<const float4*>(xp + c * BK);
            const float4 xb = *reinterpret_cast<const float4*>(xp + c * BK + 4);
            f16x8 t;
            t[0] = (_Float16)xa.x; t[1] = (_Float16)xa.y;
            t[2] = (_Float16)xa.z; t[3] = (_Float16)xa.w;
            t[4] = (_Float16)xb.x; t[5] = (_Float16)xb.y;
            t[6] = (_Float16)xb.z; t[7] = (_Float16)xb.w;
            a[c] = t;
        }
    }

    // ---- staging: wave-contiguous 1KB reads; linear LDS dest; source
    //      pre-swizzled with the involution the reader applies (rule #21) ----
    const char* wq_bytes = reinterpret_cast<const char*>(wq);
    auto stage = [&](int c, int buf) {
        #pragma unroll
        for (int p = 0; p < 2; ++p) {
            const int row = wave * 2 + p;                       // 0..15
            const int within = (lane * 16) ^ ((row & 7) << 4);  // wave-uniform XOR
            const char* src = wq_bytes + (size_t)(obase + row) * (IN_F * 4)
                                       + (size_t)c * ROW_B + within;
            char* dst = smem + buf * CH_B + row * ROW_B + lane * 16;
            __builtin_amdgcn_global_load_lds(
                (const __attribute__((address_space(1))) void*)src,
                (__attribute__((address_space(3))) void*)dst, 16, 0, 0);
        }
    };

    // retire x loads so the vmcnt ledger counts ONLY stage loads
    asm volatile("s_waitcnt vmcnt(0)" ::: "memory");

    stage(0, 0);
    stage(1, 1);
    stage(2, 2);          // outstanding: 6 loads/wave (chunks 0,1,2)

    f32x4 acc = {0.f, 0.f, 0.f, 0.f};
    const int swz = (ncol & 7) << 4;
    const int lo  = wave * 128 + kgrp * 32;   // logical byte offset in row-chunk

    #pragma unroll
    for (int c = 0; c < NCHUNK; ++c) {
        // retire chunk c's 2 loads; keep later chunks' flying (never drain
        // to 0 in steady state). Outstanding at this point:
        //   c<=13: chunks c,c+1,c+2 (6 loads) -> vmcnt(4)
        //   c==14: chunks 14,15    (4 loads) -> vmcnt(2)
        //   c==15: chunk 15        (2 loads) -> vmcnt(0)
        if (c <= NCHUNK - 3)      asm volatile("s_waitcnt vmcnt(4)" ::: "memory");
        else if (c == NCHUNK - 2) asm volatile("s_waitcnt vmcnt(2)" ::: "memory");
        else                      asm volatile("s_waitcnt vmcnt(0)" ::: "memory");
        __builtin_amdgcn_s_barrier();

        if (c + 3 < NCHUNK) stage(c + 3, (c + 3) & (NBUF - 1));  // prefetch

        const char* rowbase = smem + (c & (NBUF - 1)) * CH_B + ncol * ROW_B;
        const int4 w0 = *reinterpret_cast<const int4*>(rowbase + ((lo)      ^ swz));
        const int4 w1 = *reinterpret_cast<const int4*>(rowbase + ((lo + 16) ^ swz));
        acc = __builtin_amdgcn_mfma_f32_16x16x32_f16(a[c], cvt_codes(w0, w1), acc, 0, 0, 0);
        // NOTE: no barrier needed at loop bottom: stage(c+3) overwrites buf
        // (c+3)&3 = buf of chunk c-1, which every wave finished reading in
        // iter c-1 (lgkmcnt(0) before that MFMA precedes this iter's barrier).
    }

    // ---- reduce 8 per-wave partials (disjoint k subsets) ----
    red[wave][lane] = acc;
    __syncthreads();

    if (wave == 0) {
        f32x4 s = red[0][lane];
        #pragma unroll
        for (int w = 1; w < NWAVES; ++w) s += red[w][lane];

        const float sc = scale[0];
        const float bo = bias[obase + ncol];
        const int   brow = kgrp * 4;   // C/D: col=lane&15 -> o, row=(lane>>4)*4+r -> batch
        #pragma unroll
        for (int r = 0; r < 4; ++r)
            out[(size_t)(brow + r) * OUT_F + obase + ncol] = s[r] * sc + bo;
    }
}

extern "C" void kernel_launch(void* const* d_in, const int* in_sizes, int n_in,
                              void* d_out, int out_size, void* d_ws, size_t ws_size,
                              hipStream_t stream) {
    const float* x     = (const float*)d_in[0];
    const int*   wq    = (const int*)d_in[1];
    const float* scale = (const float*)d_in[2];
    const float* bias  = (const float*)d_in[3];
    float*       out   = (float*)d_out;

    dim3 grid(OUT_F / 16);        // 688 o-tiles
    dim3 block(NWAVES * 64);      // 512 threads
    qlinear_mfma<<<grid, block, 0, stream>>>(x, wq, scale, bias, out);
}

// Round 8
// 49.425 us; speedup vs baseline: 1.2427x; 1.0139x over previous
//
#include <hip/hip_runtime.h>
#include <stdint.h>

// CachedCompressedLinear: out[b][o] = sum_k x[b][k] * ((wq[o][k]-128)*scale) + bias[o]
// x: [16][4096] f32, wq: [11008][4096] int32 codes, scale f32, bias[11008] f32.
//
// R1..R7: four structure families (register-strided, LDS-drain, LDS-counted,
// nontemporal) ALL land at 49-61us (~3.7 TB/s on the 180MB wq read). Common
// factor: 512-thread blocks -> 16 waves/CU. R8 tests CU-level concurrency:
// 256-thread blocks, <=64 VGPR (__launch_bounds__(256,8)), 4KB LDS ->
// 8 blocks/CU = 32 waves/CU, latency hidden by TLP not per-wave MLP
// (RMSNorm-style streaming, m146: 4.89 TB/s read-dominated at full occupancy).

constexpr int IN_F  = 4096;
constexpr int OUT_F = 11008;
constexpr int NW    = 4;             // waves per block
constexpr int KPW   = IN_F / NW;     // 1024 k per wave
constexpr int NKB   = KPW / 32;      // 32 k-blocks of 32 per wave

typedef _Float16 f16x8 __attribute__((ext_vector_type(8)));
typedef float    f32x4 __attribute__((ext_vector_type(4)));

__global__ __launch_bounds__(256, 8)   // force <=64 VGPR -> 32 waves/CU
void qlinear_mfma(const float* __restrict__ x,
                  const int*   __restrict__ wq,
                  const float* __restrict__ scale,
                  const float* __restrict__ bias,
                  float*       __restrict__ out)
{
    const int tid  = threadIdx.x;
    const int lane = tid & 63;
    const int wave = tid >> 6;
    const int obase = blockIdx.x * 16;

    const int ncol = lane & 15;   // B col (o_local) == A row (batch)
    const int kgrp = lane >> 4;   // 0..3

    const int o  = obase + ncol;
    const int k0 = wave * KPW + kgrp * 8;

    const float* xp = x  + (size_t)ncol * IN_F + k0;
    const int*   wp = wq + (size_t)o    * IN_F + k0;

    f32x4 acc = {0.f, 0.f, 0.f, 0.f};

    #pragma unroll 2
    for (int kb = 0; kb < NKB; ++kb) {
        const int off = kb * 32;
        const float4 xa = *reinterpret_cast<const float4*>(xp + off);
        const float4 xb = *reinterpret_cast<const float4*>(xp + off + 4);
        const int4   wa = *reinterpret_cast<const int4*>(wp + off);
        const int4   wb = *reinterpret_cast<const int4*>(wp + off + 4);

        f16x8 af, bf;
        af[0] = (_Float16)xa.x; af[1] = (_Float16)xa.y;
        af[2] = (_Float16)xa.z; af[3] = (_Float16)xa.w;
        af[4] = (_Float16)xb.x; af[5] = (_Float16)xb.y;
        af[6] = (_Float16)xb.z; af[7] = (_Float16)xb.w;

        // codes in [0,255]; (c-128) in [-128,127] is EXACT in f16
        bf[0] = (_Float16)(wa.x - 128); bf[1] = (_Float16)(wa.y - 128);
        bf[2] = (_Float16)(wa.z - 128); bf[3] = (_Float16)(wa.w - 128);
        bf[4] = (_Float16)(wb.x - 128); bf[5] = (_Float16)(wb.y - 128);
        bf[6] = (_Float16)(wb.z - 128); bf[7] = (_Float16)(wb.w - 128);

        acc = __builtin_amdgcn_mfma_f32_16x16x32_f16(af, bf, acc, 0, 0, 0);
    }

    // ---- reduce the 4 per-wave partials (disjoint k subsets) ----
    __shared__ f32x4 red[NW][64];
    red[wave][lane] = acc;
    __syncthreads();

    if (wave == 0) {
        f32x4 s = red[0][lane];
        #pragma unroll
        for (int w = 1; w < NW; ++w) s += red[w][lane];

        const float sc = scale[0];
        const float bo = bias[o];
        const int   brow = kgrp * 4;   // C/D: col=lane&15 -> o, row=(lane>>4)*4+r -> batch
        #pragma unroll
        for (int r = 0; r < 4; ++r)
            out[(size_t)(brow + r) * OUT_F + o] = s[r] * sc + bo;
    }
}

extern "C" void kernel_launch(void* const* d_in, const int* in_sizes, int n_in,
                              void* d_out, int out_size, void* d_ws, size_t ws_size,
                              hipStream_t stream) {
    const float* x     = (const float*)d_in[0];
    const int*   wq    = (const int*)d_in[1];
    const float* scale = (const float*)d_in[2];
    const float* bias  = (const float*)d_in[3];
    float*       out   = (float*)d_out;

    dim3 grid(OUT_F / 16);   // 688 o-tiles, all co-resident at 8 blocks/CU
    dim3 block(NW * 64);     // 256 threads
    qlinear_mfma<<<grid, block, 0, stream>>>(x, wq, scale, bias, out);
}